// Round 1
// baseline (995.365 us; speedup 1.0000x reference)
//
#include <hip/hip_runtime.h>
#include <math.h>

// Problem constants
constexpr int BB = 2;
constexpr int TT = 2048;
constexpr int EE = 1024;
constexpr int HH = 16;
constexpr int DD = 64;

// ---------------------------------------------------------------------------
// GEMM: C[M,N] = A[M,K] @ W[N,K]^T + bias[N]
// MODE 0: C row-major (M,N)
// MODE 1: C written as (B,H,T,D): m=(b,t), n=(h,d)
// Tiles: 64x64, BK=16, 256 threads, 4x4 micro-tile per thread.
// ---------------------------------------------------------------------------
template <int MODE>
__global__ __launch_bounds__(256) void gemm_bias(
    const float* __restrict__ A, const float* __restrict__ W,
    const float* __restrict__ bias, float* __restrict__ C,
    int M, int N, int K)
{
    __shared__ float As[16][68];  // [k][m]
    __shared__ float Bs[16][68];  // [k][n]

    const int tid = threadIdx.x;
    const int m0 = blockIdx.y * 64;
    const int n0 = blockIdx.x * 64;
    const int tm = tid >> 4;         // 0..15 -> rows tm*4+i
    const int tn = tid & 15;         // 0..15 -> cols tn*4+j
    const int lr = tid >> 2;         // load row 0..63
    const int lk = (tid & 3) * 4;    // load k offset 0,4,8,12

    float acc[4][4] = {};

    for (int k0 = 0; k0 < K; k0 += 16) {
        float4 a4 = *(const float4*)(A + (size_t)(m0 + lr) * K + k0 + lk);
        float4 b4 = *(const float4*)(W + (size_t)(n0 + lr) * K + k0 + lk);
        __syncthreads();  // previous iteration's readers done
        As[lk + 0][lr] = a4.x; As[lk + 1][lr] = a4.y;
        As[lk + 2][lr] = a4.z; As[lk + 3][lr] = a4.w;
        Bs[lk + 0][lr] = b4.x; Bs[lk + 1][lr] = b4.y;
        Bs[lk + 2][lr] = b4.z; Bs[lk + 3][lr] = b4.w;
        __syncthreads();
        #pragma unroll
        for (int kk = 0; kk < 16; ++kk) {
            float4 av = *(const float4*)&As[kk][tm * 4];
            float4 bv = *(const float4*)&Bs[kk][tn * 4];
            float a[4] = {av.x, av.y, av.z, av.w};
            float b[4] = {bv.x, bv.y, bv.z, bv.w};
            #pragma unroll
            for (int i = 0; i < 4; ++i)
                #pragma unroll
                for (int j = 0; j < 4; ++j)
                    acc[i][j] += a[i] * b[j];
        }
    }

    #pragma unroll
    for (int i = 0; i < 4; ++i) {
        const int m = m0 + tm * 4 + i;
        #pragma unroll
        for (int j = 0; j < 4; ++j) {
            const int n = n0 + tn * 4 + j;
            const float v = acc[i][j] + bias[n];
            if (MODE == 0) {
                C[(size_t)m * N + n] = v;
            } else {
                const int b = m / TT, t = m % TT;
                const int h = n / DD, d = n % DD;
                C[(((size_t)b * HH + h) * TT + t) * DD + d] = v;
            }
        }
    }
}

// ---------------------------------------------------------------------------
// Fused attention: per block = one (b, h, 64-row q-tile).
//   phase 0: Qt = X_tile @ W_h  (W_h 64x64 in LDS, X tile overlaid on K/V LDS)
//   loop over 32-row s-tiles: S = Qt*Kt^T/8 -> online softmax -> O += P*Vt
//   epilogue: O/l written to o (B,T,E)
// ---------------------------------------------------------------------------
__global__ __launch_bounds__(256) void attn_kernel(
    const float* __restrict__ x,     // (B,T,E)
    const float* __restrict__ watt,  // (H,D,D)
    const float* __restrict__ vx,    // (B,H,T,D)
    float* __restrict__ o)           // (B,T,E)
{
    __shared__ float Qt[64][68];
    __shared__ float KV[2][32][68];  // [0]=K tile, [1]=V tile; also X tile overlay
    __shared__ float WP[4096];       // W_h (64x64) in phase 0; P tile (64x33) later
    __shared__ float m_s[64], l_s[64], a_s[64];

    const int tid = threadIdx.x;
    const int qt = blockIdx.x, h = blockIdx.y, b = blockIdx.z;
    const int t0 = qt * 64;
    const float* xb = x + (size_t)b * TT * EE;
    const float* vbase = vx + ((size_t)b * HH + h) * TT * DD;
    float* Xt = &KV[0][0][0];  // 64 x (stride 68) overlay, 4352 floats

    // ---- phase 0: load X q-tile and W_h into LDS ----
    {
        const int r = tid >> 2;            // 0..63
        const int c0 = (tid & 3) * 16;     // 0,16,32,48
        #pragma unroll
        for (int j = 0; j < 4; ++j) {
            float4 xv = *(const float4*)(xb + (size_t)(t0 + r) * EE + h * DD + c0 + j * 4);
            *(float4*)&Xt[r * 68 + c0 + j * 4] = xv;
            float4 wv = *(const float4*)(watt + (size_t)h * DD * DD + (size_t)r * DD + c0 + j * 4);
            *(float4*)&WP[r * 64 + c0 + j * 4] = wv;
        }
    }
    if (tid < 64) { m_s[tid] = -INFINITY; l_s[tid] = 0.f; }
    __syncthreads();

    const int tq = tid >> 4;  // 0..15 -> q rows tq*4+i
    const int tn = tid & 15;  // 0..15

    // ---- Qt = Xt @ W_h ----
    {
        float qa[4][4] = {};
        for (int k = 0; k < 64; ++k) {
            float xr[4];
            #pragma unroll
            for (int i = 0; i < 4; ++i) xr[i] = Xt[(tq * 4 + i) * 68 + k];
            float4 wv = *(const float4*)&WP[k * 64 + tn * 4];
            #pragma unroll
            for (int i = 0; i < 4; ++i) {
                qa[i][0] += xr[i] * wv.x; qa[i][1] += xr[i] * wv.y;
                qa[i][2] += xr[i] * wv.z; qa[i][3] += xr[i] * wv.w;
            }
        }
        #pragma unroll
        for (int i = 0; i < 4; ++i)
            #pragma unroll
            for (int j = 0; j < 4; ++j)
                Qt[tq * 4 + i][tn * 4 + j] = qa[i][j];
    }
    float oa[4][4] = {};
    __syncthreads();  // Xt/WP reads done; Qt visible

    float* Pt = WP;  // 64 rows, stride 33 (2112 floats <= 4096)

    for (int s0 = 0; s0 < TT; s0 += 32) {
        // prefetch K/V s-tile from global (before the barrier)
        const int r = tid >> 3;         // 0..31
        const int c = (tid & 7) * 8;    // 0..56
        float4 ka = *(const float4*)(xb + (size_t)(s0 + r) * EE + h * DD + c);
        float4 kb = *(const float4*)(xb + (size_t)(s0 + r) * EE + h * DD + c + 4);
        float4 va = *(const float4*)(vbase + (size_t)(s0 + r) * DD + c);
        float4 vb = *(const float4*)(vbase + (size_t)(s0 + r) * DD + c + 4);
        __syncthreads();  // prior iteration's Pt/Kt/Vt readers done
        *(float4*)&KV[0][r][c] = ka; *(float4*)&KV[0][r][c + 4] = kb;
        *(float4*)&KV[1][r][c] = va; *(float4*)&KV[1][r][c + 4] = vb;
        __syncthreads();

        // scores: 4 q-rows x 2 s-cols per thread
        float sc[4][2] = {};
        #pragma unroll 4
        for (int k4 = 0; k4 < 16; ++k4) {
            float4 qv[4], kv[2];
            #pragma unroll
            for (int i = 0; i < 4; ++i) qv[i] = *(const float4*)&Qt[tq * 4 + i][k4 * 4];
            #pragma unroll
            for (int j = 0; j < 2; ++j) kv[j] = *(const float4*)&KV[0][tn * 2 + j][k4 * 4];
            #pragma unroll
            for (int i = 0; i < 4; ++i)
                #pragma unroll
                for (int j = 0; j < 2; ++j)
                    sc[i][j] += qv[i].x * kv[j].x + qv[i].y * kv[j].y +
                                qv[i].z * kv[j].z + qv[i].w * kv[j].w;
        }
        #pragma unroll
        for (int i = 0; i < 4; ++i)
            #pragma unroll
            for (int j = 0; j < 2; ++j)
                Pt[(tq * 4 + i) * 33 + tn * 2 + j] = sc[i][j] * 0.125f;
        __syncthreads();

        // online softmax row pass (one thread per q-row)
        if (tid < 64) {
            float* row = &Pt[tid * 33];
            const float mo = m_s[tid];
            float tmax = -INFINITY;
            for (int j = 0; j < 32; ++j) tmax = fmaxf(tmax, row[j]);
            const float nm = fmaxf(mo, tmax);
            const float al = __expf(mo - nm);
            float sum = 0.f;
            for (int j = 0; j < 32; ++j) {
                const float p = __expf(row[j] - nm);
                row[j] = p;
                sum += p;
            }
            l_s[tid] = l_s[tid] * al + sum;
            m_s[tid] = nm;
            a_s[tid] = al;
        }
        __syncthreads();

        // rescale O, then O += P @ Vt  (4 q-rows x 4 d-cols per thread)
        float al[4];
        #pragma unroll
        for (int i = 0; i < 4; ++i) al[i] = a_s[tq * 4 + i];
        #pragma unroll
        for (int i = 0; i < 4; ++i)
            #pragma unroll
            for (int j = 0; j < 4; ++j)
                oa[i][j] *= al[i];
        #pragma unroll 4
        for (int s = 0; s < 32; ++s) {
            float p[4];
            #pragma unroll
            for (int i = 0; i < 4; ++i) p[i] = Pt[(tq * 4 + i) * 33 + s];
            float4 vv = *(const float4*)&KV[1][s][tn * 4];
            #pragma unroll
            for (int i = 0; i < 4; ++i) {
                oa[i][0] += p[i] * vv.x; oa[i][1] += p[i] * vv.y;
                oa[i][2] += p[i] * vv.z; oa[i][3] += p[i] * vv.w;
            }
        }
        // next iteration's first __syncthreads() protects Pt/Kt/Vt overwrite
    }

    // epilogue: divide by l, store to o (B,T,E)
    #pragma unroll
    for (int i = 0; i < 4; ++i) {
        const float li = 1.0f / l_s[tq * 4 + i];
        float4 ov = make_float4(oa[i][0] * li, oa[i][1] * li, oa[i][2] * li, oa[i][3] * li);
        *(float4*)(o + ((size_t)b * TT + t0 + tq * 4 + i) * EE + h * DD + tn * 4) = ov;
    }
}

// ---------------------------------------------------------------------------
extern "C" void kernel_launch(void* const* d_in, const int* in_sizes, int n_in,
                              void* d_out, int out_size, void* d_ws, size_t ws_size,
                              hipStream_t stream)
{
    const float* x     = (const float*)d_in[0];
    const float* watt  = (const float*)d_in[1];
    const float* wv_w  = (const float*)d_in[2];
    const float* wv_b  = (const float*)d_in[3];
    const float* out_w = (const float*)d_in[4];
    const float* out_b = (const float*)d_in[5];
    float* out = (float*)d_out;

    float* vx = (float*)d_ws;                         // B*H*T*D floats
    float* o  = vx + (size_t)BB * HH * TT * DD;       // B*T*E floats

    const int M = BB * TT;  // 4096
    dim3 gg(EE / 64, M / 64);

    // vx = x @ wv_w^T + wv_b, stored as (B,H,T,D)
    gemm_bias<1><<<gg, 256, 0, stream>>>(x, wv_w, wv_b, vx, M, EE, EE);

    // fused bilinear attention -> o (B,T,E)
    dim3 ga(TT / 64, HH, BB);
    attn_kernel<<<ga, 256, 0, stream>>>(x, watt, vx, o);

    // out = o @ out_w^T + out_b
    gemm_bias<0><<<gg, 256, 0, stream>>>(o, out_w, out_b, out, M, EE, EE);
}

// Round 2
// 532.033 us; speedup vs baseline: 1.8709x; 1.8709x over previous
//
#include <hip/hip_runtime.h>
#include <math.h>

// Problem constants
constexpr int BB = 2;
constexpr int TT = 2048;
constexpr int EE = 1024;
constexpr int HH = 16;
constexpr int DD = 64;

typedef __bf16 v8bf __attribute__((ext_vector_type(8)));
typedef float  v4f  __attribute__((ext_vector_type(4)));

#define MFMA16(a, b, c) __builtin_amdgcn_mfma_f32_16x16x32_bf16(a, b, c, 0, 0, 0)

// ---------------------------------------------------------------------------
// GEMM: C[M,N] = A[M,K] @ W[N,K]^T + bias[N]   (unchanged fp32 from round 1)
// MODE 0: C row-major (M,N);  MODE 1: C written as (B,H,T,D)
// ---------------------------------------------------------------------------
template <int MODE>
__global__ __launch_bounds__(256) void gemm_bias(
    const float* __restrict__ A, const float* __restrict__ W,
    const float* __restrict__ bias, float* __restrict__ C,
    int M, int N, int K)
{
    __shared__ float As[16][68];  // [k][m]
    __shared__ float Bs[16][68];  // [k][n]

    const int tid = threadIdx.x;
    const int m0 = blockIdx.y * 64;
    const int n0 = blockIdx.x * 64;
    const int tm = tid >> 4;
    const int tn = tid & 15;
    const int lr = tid >> 2;
    const int lk = (tid & 3) * 4;

    float acc[4][4] = {};

    for (int k0 = 0; k0 < K; k0 += 16) {
        float4 a4 = *(const float4*)(A + (size_t)(m0 + lr) * K + k0 + lk);
        float4 b4 = *(const float4*)(W + (size_t)(n0 + lr) * K + k0 + lk);
        __syncthreads();
        As[lk + 0][lr] = a4.x; As[lk + 1][lr] = a4.y;
        As[lk + 2][lr] = a4.z; As[lk + 3][lr] = a4.w;
        Bs[lk + 0][lr] = b4.x; Bs[lk + 1][lr] = b4.y;
        Bs[lk + 2][lr] = b4.z; Bs[lk + 3][lr] = b4.w;
        __syncthreads();
        #pragma unroll
        for (int kk = 0; kk < 16; ++kk) {
            float4 av = *(const float4*)&As[kk][tm * 4];
            float4 bv = *(const float4*)&Bs[kk][tn * 4];
            float a[4] = {av.x, av.y, av.z, av.w};
            float b[4] = {bv.x, bv.y, bv.z, bv.w};
            #pragma unroll
            for (int i = 0; i < 4; ++i)
                #pragma unroll
                for (int j = 0; j < 4; ++j)
                    acc[i][j] += a[i] * b[j];
        }
    }

    #pragma unroll
    for (int i = 0; i < 4; ++i) {
        const int m = m0 + tm * 4 + i;
        #pragma unroll
        for (int j = 0; j < 4; ++j) {
            const int n = n0 + tn * 4 + j;
            const float v = acc[i][j] + bias[n];
            if (MODE == 0) {
                C[(size_t)m * N + n] = v;
            } else {
                const int b = m / TT, t = m % TT;
                const int h = n / DD, d = n % DD;
                C[(((size_t)b * HH + h) * TT + t) * DD + d] = v;
            }
        }
    }
}

// ---------------------------------------------------------------------------
// MFMA flash attention.  Block = (b, h, 64-row q-tile), 4 waves.
// LDS regions (each 64 x 72 bf16):
//   0 = K hi   (phase 0: X hi)
//   1 = K lo   (phase 0: X lo)
//   2 = V^T    (phase 0: W_h^T hi)
//   3 = Q hi   (loop: P tile)
//   4 = Q lo   (phase 0: W_h^T lo)
// ---------------------------------------------------------------------------
__global__ __launch_bounds__(256, 3) void attn_mfma(
    const float* __restrict__ x,     // (B,T,E)
    const float* __restrict__ watt,  // (H,D,D)
    const float* __restrict__ vx,    // (B,H,T,D)
    float* __restrict__ o)           // (B,T,E)
{
    constexpr int LDP = 72;
    __shared__ __bf16 lds[5][64][LDP];

    const int tid  = threadIdx.x;
    const int w    = tid >> 6;
    const int lane = tid & 63;
    const int quad = lane >> 4;
    const int l15  = lane & 15;
    const int qt = blockIdx.x, h = blockIdx.y, b = blockIdx.z;
    const int t0 = qt * 64;

    const float* xb    = x + (size_t)b * TT * EE;
    const float* vbase = vx + ((size_t)b * HH + h) * TT * DD;

    const int sr = tid >> 2;          // staging row 0..63
    const int sc = (tid & 3) * 16;    // staging col 0,16,32,48

    const v4f vzero = {0.f, 0.f, 0.f, 0.f};

    // ---- phase 0: stage X q-tile (straight hi/lo) and W_h (transposed hi/lo)
    {
        const float* xp = xb + (size_t)(t0 + sr) * EE + h * DD + sc;
        const float* wp = watt + ((size_t)h * DD + sr) * DD + sc;
        float4 xt[4], wt[4];
        #pragma unroll
        for (int i = 0; i < 4; ++i) {
            xt[i] = ((const float4*)xp)[i];
            wt[i] = ((const float4*)wp)[i];
        }
        const float* xf = (const float*)xt;
        const float* wf = (const float*)wt;
        #pragma unroll
        for (int i = 0; i < 16; ++i) {
            __bf16 hx = (__bf16)xf[i];
            lds[0][sr][sc + i] = hx;
            lds[1][sr][sc + i] = (__bf16)(xf[i] - (float)hx);
            __bf16 hw = (__bf16)wf[i];
            lds[2][sc + i][sr] = hw;                       // W^T hi
            lds[4][sc + i][sr] = (__bf16)(wf[i] - (float)hw);  // W^T lo
        }
    }
    __syncthreads();

    // ---- Q = X @ W_h  (split-3 MFMA; wave w computes rows [16w,16w+16))
    v4f qacc[4];
    #pragma unroll
    for (int s = 0; s < 4; ++s) qacc[s] = vzero;
    #pragma unroll
    for (int kk = 0; kk < 2; ++kk) {
        v8bf xh = *(const v8bf*)&lds[0][16 * w + l15][kk * 32 + quad * 8];
        v8bf xl = *(const v8bf*)&lds[1][16 * w + l15][kk * 32 + quad * 8];
        #pragma unroll
        for (int s = 0; s < 4; ++s) {
            v8bf wh = *(const v8bf*)&lds[2][s * 16 + l15][kk * 32 + quad * 8];
            v8bf wl = *(const v8bf*)&lds[4][s * 16 + l15][kk * 32 + quad * 8];
            qacc[s] = MFMA16(xl, wh, qacc[s]);
            qacc[s] = MFMA16(xh, wl, qacc[s]);
            qacc[s] = MFMA16(xh, wh, qacc[s]);
        }
    }
    __syncthreads();  // all waves done reading X / W^T regions

    // write Q hi/lo (C-layout scatter, wave-local rows), reload as A-frags
    #pragma unroll
    for (int s = 0; s < 4; ++s)
        #pragma unroll
        for (int r = 0; r < 4; ++r) {
            float v = qacc[s][r];
            __bf16 hi = (__bf16)v;
            lds[3][16 * w + quad * 4 + r][s * 16 + l15] = hi;
            lds[4][16 * w + quad * 4 + r][s * 16 + l15] = (__bf16)(v - (float)hi);
        }
    v8bf qh[2], qlo[2];
    #pragma unroll
    for (int kk = 0; kk < 2; ++kk) {
        qh[kk]  = *(const v8bf*)&lds[3][16 * w + l15][kk * 32 + quad * 8];
        qlo[kk] = *(const v8bf*)&lds[4][16 * w + l15][kk * 32 + quad * 8];
    }

    v4f oacc[4];
    #pragma unroll
    for (int s = 0; s < 4; ++s) oacc[s] = vzero;
    float ml[4], ll[4];
    #pragma unroll
    for (int r = 0; r < 4; ++r) { ml[r] = -INFINITY; ll[r] = 0.f; }

    // ---- main loop over 64-row s-tiles ----
    for (int s0 = 0; s0 < TT; s0 += 64) {
        // global loads first (land in VGPRs, overlap with barrier)
        float4 kt[4], vt4[4];
        const float* kp = xb + (size_t)(s0 + sr) * EE + h * DD + sc;
        const float* vp = vbase + (size_t)(s0 + sr) * DD + sc;
        #pragma unroll
        for (int i = 0; i < 4; ++i) {
            kt[i]  = ((const float4*)kp)[i];
            vt4[i] = ((const float4*)vp)[i];
        }
        __syncthreads();  // (a) prior iteration's K/V readers done
        {
            const float* kf = (const float*)kt;
            const float* vf = (const float*)vt4;
            #pragma unroll
            for (int i = 0; i < 16; ++i) {
                __bf16 hk = (__bf16)kf[i];
                lds[0][sr][sc + i] = hk;
                lds[1][sr][sc + i] = (__bf16)(kf[i] - (float)hk);
                lds[2][sc + i][sr] = (__bf16)vf[i];  // V^T, single bf16
            }
        }
        __syncthreads();  // (b) staging visible

        // S = Q K^T (split-3)
        v4f sacc[4];
        #pragma unroll
        for (int s = 0; s < 4; ++s) sacc[s] = vzero;
        #pragma unroll
        for (int kk = 0; kk < 2; ++kk) {
            #pragma unroll
            for (int s = 0; s < 4; ++s) {
                v8bf kh = *(const v8bf*)&lds[0][s * 16 + l15][kk * 32 + quad * 8];
                v8bf kl = *(const v8bf*)&lds[1][s * 16 + l15][kk * 32 + quad * 8];
                sacc[s] = MFMA16(qlo[kk], kh, sacc[s]);
                sacc[s] = MFMA16(qh[kk],  kl, sacc[s]);
                sacc[s] = MFMA16(qh[kk],  kh, sacc[s]);
            }
        }

        // online softmax: row = 16w + quad*4 + r, cols distributed over l15 + 4 subtiles
        float alpha[4], p[4][4];
        #pragma unroll
        for (int r = 0; r < 4; ++r) {
            float t = fmaxf(fmaxf(sacc[0][r], sacc[1][r]),
                            fmaxf(sacc[2][r], sacc[3][r])) * 0.125f;
            t = fmaxf(t, __shfl_xor(t, 1));
            t = fmaxf(t, __shfl_xor(t, 2));
            t = fmaxf(t, __shfl_xor(t, 4));
            t = fmaxf(t, __shfl_xor(t, 8));
            const float mnew = fmaxf(ml[r], t);
            alpha[r] = __expf(ml[r] - mnew);
            float ps = 0.f;
            #pragma unroll
            for (int s = 0; s < 4; ++s) {
                p[s][r] = __expf(sacc[s][r] * 0.125f - mnew);
                ps += p[s][r];
            }
            ps += __shfl_xor(ps, 1);
            ps += __shfl_xor(ps, 2);
            ps += __shfl_xor(ps, 4);
            ps += __shfl_xor(ps, 8);
            ll[r] = ll[r] * alpha[r] + ps;
            ml[r] = mnew;
        }

        // P -> LDS (C-layout scatter, wave-local rows of region 3)
        #pragma unroll
        for (int s = 0; s < 4; ++s)
            #pragma unroll
            for (int r = 0; r < 4; ++r)
                lds[3][16 * w + quad * 4 + r][s * 16 + l15] = (__bf16)p[s][r];

        // rescale O
        #pragma unroll
        for (int s = 0; s < 4; ++s)
            #pragma unroll
            for (int r = 0; r < 4; ++r)
                oacc[s][r] *= alpha[r];

        // O += P @ V  (A = P from LDS, B = V^T rows)
        #pragma unroll
        for (int kk = 0; kk < 2; ++kk) {
            v8bf pf = *(const v8bf*)&lds[3][16 * w + l15][kk * 32 + quad * 8];
            #pragma unroll
            for (int s = 0; s < 4; ++s) {
                v8bf vf = *(const v8bf*)&lds[2][s * 16 + l15][kk * 32 + quad * 8];
                oacc[s] = MFMA16(pf, vf, oacc[s]);
            }
        }
    }

    // ---- epilogue: O / l -> o (B,T,E), C-layout scatter ----
    #pragma unroll
    for (int s = 0; s < 4; ++s) {
        #pragma unroll
        for (int r = 0; r < 4; ++r) {
            const float val = oacc[s][r] / ll[r];
            o[((size_t)b * TT + t0 + 16 * w + quad * 4 + r) * EE + h * DD + s * 16 + l15] = val;
        }
    }
}

// ---------------------------------------------------------------------------
extern "C" void kernel_launch(void* const* d_in, const int* in_sizes, int n_in,
                              void* d_out, int out_size, void* d_ws, size_t ws_size,
                              hipStream_t stream)
{
    const float* x     = (const float*)d_in[0];
    const float* watt  = (const float*)d_in[1];
    const float* wv_w  = (const float*)d_in[2];
    const float* wv_b  = (const float*)d_in[3];
    const float* out_w = (const float*)d_in[4];
    const float* out_b = (const float*)d_in[5];
    float* out = (float*)d_out;

    float* vx = (float*)d_ws;                    // B*H*T*D floats
    float* o  = vx + (size_t)BB * HH * TT * DD;  // B*T*E floats

    const int M = BB * TT;  // 4096
    dim3 gg(EE / 64, M / 64);

    // vx = x @ wv_w^T + wv_b, stored as (B,H,T,D)
    gemm_bias<1><<<gg, 256, 0, stream>>>(x, wv_w, wv_b, vx, M, EE, EE);

    // fused bilinear attention -> o (B,T,E)
    dim3 ga(TT / 64, HH, BB);
    attn_mfma<<<ga, 256, 0, stream>>>(x, watt, vx, o);

    // out = o @ out_w^T + out_b
    gemm_bias<0><<<gg, 256, 0, stream>>>(o, out_w, out_b, out, M, EE, EE);
}

// Round 4
// 206.131 us; speedup vs baseline: 4.8288x; 2.5810x over previous
//
#include <hip/hip_runtime.h>
#include <hip/hip_bf16.h>
#include <math.h>

constexpr int BB = 2;
constexpr int TT = 2048;
constexpr int EE = 1024;
constexpr int HH = 16;
constexpr int DD = 64;

typedef __bf16 v8bf __attribute__((ext_vector_type(8)));
typedef __bf16 v4bf __attribute__((ext_vector_type(4)));
typedef float  v4f  __attribute__((ext_vector_type(4)));

#define MFMA16(a, b, c) __builtin_amdgcn_mfma_f32_16x16x32_bf16(a, b, c, 0, 0, 0)

// ---------------------------------------------------------------------------
// cast_all: x -> x_hi (bf16), wv_w -> bf16, out_w -> bf16.  8 elems/thread.
// block partition: [0,2048) x, [2048,2560) wv_w, [2560,3072) out_w
// ---------------------------------------------------------------------------
__global__ __launch_bounds__(256) void cast_all(
    const float* __restrict__ x, const float* __restrict__ wv,
    const float* __restrict__ ow,
    __bf16* __restrict__ xhi, __bf16* __restrict__ wvb, __bf16* __restrict__ owb)
{
    const int bid = blockIdx.x;
    const float* src;
    __bf16* dst;
    int base;
    if (bid < 2048)      { src = x;  dst = xhi; base = bid; }
    else if (bid < 2560) { src = wv; dst = wvb; base = bid - 2048; }
    else                 { src = ow; dst = owb; base = bid - 2560; }
    const size_t i = (size_t)base * 256 + threadIdx.x;
    float4 f0 = ((const float4*)src)[i * 2];
    float4 f1 = ((const float4*)src)[i * 2 + 1];
    float f[8] = {f0.x, f0.y, f0.z, f0.w, f1.x, f1.y, f1.z, f1.w};
    v8bf h;
    #pragma unroll
    for (int j = 0; j < 8; ++j) h[j] = (__bf16)f[j];
    *(v8bf*)(dst + i * 8) = h;
}

// ---------------------------------------------------------------------------
// bf16 MFMA GEMM: C[M,N] = A[M,K](bf16) @ Bw[N,K](bf16)^T + bias
// Tile 128(M) x 64(N), BK=32, 256 threads (4 waves, each 64x32).
// MODE 0: C fp32 row-major (M,N)
// MODE 1: C bf16 written as vxT (B,H,D,T): m=(b,t), n=(h,d)
// LDP=40 is correct HERE: staged k-columns are 0..31 only.
// ---------------------------------------------------------------------------
template <int MODE>
__global__ __launch_bounds__(256) void gemm_bf16(
    const __bf16* __restrict__ A, const __bf16* __restrict__ Bw,
    const float* __restrict__ bias, void* __restrict__ Cout,
    int M, int N, int K)
{
    constexpr int LDP = 40;
    __shared__ __bf16 Ah[128][LDP];
    __shared__ __bf16 Bh[64][LDP];

    const int tid = threadIdx.x;
    const int w = tid >> 6, lane = tid & 63, quad = lane >> 4, l15 = lane & 15;
    const int m0 = blockIdx.y * 128, n0 = blockIdx.x * 64;
    const int wm = (w >> 1) * 64, wn = (w & 1) * 32;

    v4f acc[4][2] = {};
    float bn[2];
    #pragma unroll
    for (int ns = 0; ns < 2; ++ns) bn[ns] = bias[n0 + wn + ns * 16 + l15];

    const int ra = tid >> 2;          // 0..63
    const int ca = (tid & 3) * 8;     // 0,8,16,24

    for (int k0 = 0; k0 < K; k0 += 32) {
        uint4 a0 = *(const uint4*)(A + (size_t)(m0 + ra) * K + k0 + ca);
        uint4 a1 = *(const uint4*)(A + (size_t)(m0 + ra + 64) * K + k0 + ca);
        uint4 b0 = *(const uint4*)(Bw + (size_t)(n0 + ra) * K + k0 + ca);
        __syncthreads();
        *(uint4*)&Ah[ra][ca] = a0;
        *(uint4*)&Ah[ra + 64][ca] = a1;
        *(uint4*)&Bh[ra][ca] = b0;
        __syncthreads();
        v8bf af[4], bf2[2];
        #pragma unroll
        for (int ms = 0; ms < 4; ++ms)
            af[ms] = *(const v8bf*)&Ah[wm + ms * 16 + l15][quad * 8];
        #pragma unroll
        for (int ns = 0; ns < 2; ++ns)
            bf2[ns] = *(const v8bf*)&Bh[wn + ns * 16 + l15][quad * 8];
        #pragma unroll
        for (int ms = 0; ms < 4; ++ms)
            #pragma unroll
            for (int ns = 0; ns < 2; ++ns)
                acc[ms][ns] = MFMA16(af[ms], bf2[ns], acc[ms][ns]);
    }

    #pragma unroll
    for (int ms = 0; ms < 4; ++ms) {
        const int mbase = m0 + wm + ms * 16 + quad * 4;
        #pragma unroll
        for (int ns = 0; ns < 2; ++ns) {
            const int n = n0 + wn + ns * 16 + l15;
            if (MODE == 0) {
                float* C = (float*)Cout;
                #pragma unroll
                for (int r = 0; r < 4; ++r)
                    C[(size_t)(mbase + r) * N + n] = acc[ms][ns][r] + bn[ns];
            } else {
                const int bq = mbase >> 11, t = mbase & 2047;
                const int hh = n >> 6, dd = n & 63;
                v4bf pk;
                #pragma unroll
                for (int r = 0; r < 4; ++r) pk[r] = (__bf16)(acc[ms][ns][r] + bn[ns]);
                *(v4bf*)((__bf16*)Cout + (((size_t)bq * HH + hh) * DD + dd) * TT + t) = pk;
            }
        }
    }
}

// ---------------------------------------------------------------------------
// MFMA flash attention, max-free softmax.
// Block = (b, h, 128 q-rows), 4 waves; wave owns 32 q-rows (2 m-reps).
// S = (Q_hi + Q_lo) K  (K single bf16; Q split hi/lo, W/8 folded).
// LDS (LDP=72 — tiles are 64 wide + pad; round-3 bug was LDP=40 here):
//   Khi[64]  : ph0 Wt_hi   ; loop K tile
//   Vt [64]  : ph0 Wt_lo   ; loop V^T tile
//   Pm [128] : ph0 X_hi    ; then Q_hi scatter ; loop P
//   Xlo[128] : ph0 X_lo    ; then Q_lo scatter
// 54 KB -> 2 blocks/CU; attn grid is 512 blocks = 2/CU, so no occupancy loss.
// ---------------------------------------------------------------------------
__global__ __launch_bounds__(256) void attn_mfma(
    const float* __restrict__ x,      // (B,T,E) fp32 (phase-0 Q input)
    const __bf16* __restrict__ xh,    // (B,T,E) bf16 (K)
    const float* __restrict__ watt,   // (H,D,D) fp32
    const __bf16* __restrict__ vxT,   // (B,H,D,T) bf16
    __bf16* __restrict__ o)           // (B,T,E) bf16
{
    constexpr int LDP = 72;
    __shared__ __bf16 Khi[64][LDP];
    __shared__ __bf16 Vt[64][LDP];
    __shared__ __bf16 Pm[128][LDP];
    __shared__ __bf16 Xlo[128][LDP];

    const int tid = threadIdx.x;
    const int w = tid >> 6, lane = tid & 63, quad = lane >> 4, l15 = lane & 15;
    const int qt = blockIdx.x, h = blockIdx.y, b = blockIdx.z;
    const int t0 = qt * 128;

    // ---- phase 0: stage X q-tile (fp32 -> hi/lo) and W_h^T (scaled, hi/lo)
    {
        const int row = tid >> 1, half = (tid & 1) * 32;
        const float* xp = x + ((size_t)(b * TT + t0 + row)) * EE + h * DD + half;
        #pragma unroll
        for (int c = 0; c < 4; ++c) {
            float4 f0 = ((const float4*)xp)[c * 2];
            float4 f1 = ((const float4*)xp)[c * 2 + 1];
            float f[8] = {f0.x, f0.y, f0.z, f0.w, f1.x, f1.y, f1.z, f1.w};
            v8bf hi, lo;
            #pragma unroll
            for (int j = 0; j < 8; ++j) {
                __bf16 hv = (__bf16)f[j];
                hi[j] = hv;
                lo[j] = (__bf16)(f[j] - (float)hv);
            }
            *(v8bf*)&Pm[row][half + c * 8] = hi;
            *(v8bf*)&Xlo[row][half + c * 8] = lo;
        }
        const int r = tid >> 2, c0 = (tid & 3) * 16;
        const float* wp = watt + ((size_t)h * DD + r) * DD + c0;
        #pragma unroll
        for (int i = 0; i < 16; ++i) {
            const float f = wp[i] * 0.125f;  // fold 1/sqrt(D) scale into W
            __bf16 hv = (__bf16)f;
            Khi[c0 + i][r] = hv;                      // Wt_hi[e_out][d]
            Vt[c0 + i][r] = (__bf16)(f - (float)hv);  // Wt_lo
        }
    }
    __syncthreads();

    // ---- Q = X_hi Wt_hi + X_hi Wt_lo + X_lo Wt_hi  (wave-local 32 rows)
    v4f qacc[2][4] = {};
    #pragma unroll
    for (int kk = 0; kk < 2; ++kk) {
        #pragma unroll
        for (int mr = 0; mr < 2; ++mr) {
            v8bf xhf = *(const v8bf*)&Pm[w * 32 + mr * 16 + l15][kk * 32 + quad * 8];
            v8bf xlf = *(const v8bf*)&Xlo[w * 32 + mr * 16 + l15][kk * 32 + quad * 8];
            #pragma unroll
            for (int ns = 0; ns < 4; ++ns) {
                v8bf wh = *(const v8bf*)&Khi[ns * 16 + l15][kk * 32 + quad * 8];
                v8bf wl = *(const v8bf*)&Vt[ns * 16 + l15][kk * 32 + quad * 8];
                qacc[mr][ns] = MFMA16(xlf, wh, qacc[mr][ns]);
                qacc[mr][ns] = MFMA16(xhf, wl, qacc[mr][ns]);
                qacc[mr][ns] = MFMA16(xhf, wh, qacc[mr][ns]);
            }
        }
    }
    __syncthreads();  // all waves done reading Pm/Xlo/Khi/Vt

    // write Q hi/lo (C-layout scatter, wave-local rows), reload as A-frags
    #pragma unroll
    for (int mr = 0; mr < 2; ++mr)
        #pragma unroll
        for (int ns = 0; ns < 4; ++ns)
            #pragma unroll
            for (int r = 0; r < 4; ++r) {
                const float f = qacc[mr][ns][r];
                __bf16 hv = (__bf16)f;
                Pm[w * 32 + mr * 16 + quad * 4 + r][ns * 16 + l15] = hv;
                Xlo[w * 32 + mr * 16 + quad * 4 + r][ns * 16 + l15] = (__bf16)(f - (float)hv);
            }
    v8bf qh[2][2], ql[2][2];
    #pragma unroll
    for (int mr = 0; mr < 2; ++mr)
        #pragma unroll
        for (int kk = 0; kk < 2; ++kk) {
            qh[mr][kk] = *(const v8bf*)&Pm[w * 32 + mr * 16 + l15][kk * 32 + quad * 8];
            ql[mr][kk] = *(const v8bf*)&Xlo[w * 32 + mr * 16 + l15][kk * 32 + quad * 8];
        }

    v4f oacc[2][4] = {};
    float ll[2][4] = {};

    const __bf16* kb = xh + (size_t)b * TT * EE + h * DD;
    const __bf16* vb = vxT + ((size_t)(b * HH + h)) * DD * TT;

    // ---- main loop over 64-row s-tiles ----
    for (int s0 = 0; s0 < TT; s0 += 64) {
        const int r0 = tid >> 3, c0 = (tid & 7) * 8;   // rows 0..31
        const int r1 = r0 + 32;                        // rows 32..63
        uint4 kv0 = *(const uint4*)(kb + (size_t)(s0 + r0) * EE + c0);
        uint4 kv1 = *(const uint4*)(kb + (size_t)(s0 + r1) * EE + c0);
        uint4 vv0 = *(const uint4*)(vb + (size_t)r0 * TT + s0 + c0);
        uint4 vv1 = *(const uint4*)(vb + (size_t)r1 * TT + s0 + c0);
        __syncthreads();  // prior iteration's K/V readers done
        *(uint4*)&Khi[r0][c0] = kv0;
        *(uint4*)&Khi[r1][c0] = kv1;
        *(uint4*)&Vt[r0][c0] = vv0;
        *(uint4*)&Vt[r1][c0] = vv1;
        __syncthreads();

        // S = Q_hi K + Q_lo K
        v4f sacc[2][4] = {};
        #pragma unroll
        for (int kk = 0; kk < 2; ++kk)
            #pragma unroll
            for (int ss = 0; ss < 4; ++ss) {
                v8bf kf = *(const v8bf*)&Khi[ss * 16 + l15][kk * 32 + quad * 8];
                #pragma unroll
                for (int mr = 0; mr < 2; ++mr) {
                    sacc[mr][ss] = MFMA16(ql[mr][kk], kf, sacc[mr][ss]);
                    sacc[mr][ss] = MFMA16(qh[mr][kk], kf, sacc[mr][ss]);
                }
            }

        // exp (no max subtraction), P -> LDS (wave-local rows), l partials
        #pragma unroll
        for (int mr = 0; mr < 2; ++mr)
            #pragma unroll
            for (int ss = 0; ss < 4; ++ss)
                #pragma unroll
                for (int r = 0; r < 4; ++r) {
                    const float p = __expf(sacc[mr][ss][r]);
                    ll[mr][r] += p;
                    Pm[w * 32 + mr * 16 + quad * 4 + r][ss * 16 + l15] = (__bf16)p;
                }

        // O += P @ V   (P rows are wave-private: no barrier needed)
        #pragma unroll
        for (int kk = 0; kk < 2; ++kk) {
            v8bf pf0 = *(const v8bf*)&Pm[w * 32 + l15][kk * 32 + quad * 8];
            v8bf pf1 = *(const v8bf*)&Pm[w * 32 + 16 + l15][kk * 32 + quad * 8];
            #pragma unroll
            for (int ds = 0; ds < 4; ++ds) {
                v8bf vf = *(const v8bf*)&Vt[ds * 16 + l15][kk * 32 + quad * 8];
                oacc[0][ds] = MFMA16(pf0, vf, oacc[0][ds]);
                oacc[1][ds] = MFMA16(pf1, vf, oacc[1][ds]);
            }
        }
    }

    // ---- epilogue: reduce l across the 16 lanes of each quad, store O/l ----
    float inv[2][4];
    #pragma unroll
    for (int mr = 0; mr < 2; ++mr)
        #pragma unroll
        for (int r = 0; r < 4; ++r) {
            float s = ll[mr][r];
            s += __shfl_xor(s, 1);
            s += __shfl_xor(s, 2);
            s += __shfl_xor(s, 4);
            s += __shfl_xor(s, 8);
            inv[mr][r] = 1.0f / s;
        }
    #pragma unroll
    for (int mr = 0; mr < 2; ++mr)
        #pragma unroll
        for (int ds = 0; ds < 4; ++ds)
            #pragma unroll
            for (int r = 0; r < 4; ++r) {
                const float val = oacc[mr][ds][r] * inv[mr][r];
                o[(size_t)(b * TT + t0 + w * 32 + mr * 16 + quad * 4 + r) * EE +
                  h * DD + ds * 16 + l15] = (__bf16)val;
            }
}

// ---------------------------------------------------------------------------
extern "C" void kernel_launch(void* const* d_in, const int* in_sizes, int n_in,
                              void* d_out, int out_size, void* d_ws, size_t ws_size,
                              hipStream_t stream)
{
    const float* x     = (const float*)d_in[0];
    const float* watt  = (const float*)d_in[1];
    const float* wv_w  = (const float*)d_in[2];
    const float* wv_b  = (const float*)d_in[3];
    const float* out_w = (const float*)d_in[4];
    const float* out_b = (const float*)d_in[5];
    float* out = (float*)d_out;

    __bf16* xhi = (__bf16*)d_ws;                         // B*T*E
    __bf16* wvb = xhi + (size_t)BB * TT * EE;            // E*E
    __bf16* owb = wvb + (size_t)EE * EE;                 // E*E
    __bf16* vxT = owb + (size_t)EE * EE;                 // B*H*D*T
    __bf16* obf = vxT + (size_t)BB * HH * DD * TT;       // B*T*E

    const int M = BB * TT;  // 4096

    // casts: x -> bf16 hi, wv_w -> bf16, out_w -> bf16
    cast_all<<<3072, 256, 0, stream>>>(x, wv_w, out_w, xhi, wvb, owb);

    // vx = x @ wv_w^T + wv_b, written transposed bf16 as (B,H,D,T)
    gemm_bf16<1><<<dim3(EE / 64, M / 128), 256, 0, stream>>>(
        xhi, wvb, wv_b, (void*)vxT, M, EE, EE);

    // fused bilinear attention -> obf (B,T,E) bf16
    attn_mfma<<<dim3(TT / 128, HH, BB), 256, 0, stream>>>(x, xhi, watt, vxT, obf);

    // out = o @ out_w^T + out_b (fp32 out)
    gemm_bf16<0><<<dim3(EE / 64, M / 128), 256, 0, stream>>>(
        obf, owb, out_b, (void*)out, M, EE, EE);
}